// Round 4
// baseline (158.442 us; speedup 1.0000x reference)
//
#include <hip/hip_runtime.h>

// B=8, Cin=Cout=32, H=W=256, K=5. Adaptive bins: start (k*256)/5, all length 52.
// filt = pooled feat / 52^2.
// out[b,o,y,x] = sum_{kh,kw} filt[b,o,kh,kw] * feat[b,o,y-2+kh,x-2+kw]  (zero pad 2)

#define CIN 32
#define COUT 32
#define HW 256
#define PLANE (HW * HW)
#define BATCH 8
#define KF 5
#define BIN 52

// ---------------- K1: 1x1 conv + fused adaptive-pool partials ----------------
// Block = one (b,row), 256 threads = 256 cols. NO LDS staging for the conv:
// direct chunked global loads keep VGPR ~60 (8 waves/SIMD eligible) and avoid
// the stage->sync phase serialization. LDS (32KB) used only for the pool reduce.
__global__ __launch_bounds__(256) void conv1x1_pool_kernel(const float* __restrict__ x,
                                                           const float* __restrict__ Wm,
                                                           const float* __restrict__ bias,
                                                           float* __restrict__ feat,
                                                           float* __restrict__ filt_raw) {
    int b   = blockIdx.x >> 8;      // 0..7
    int row = blockIdx.x & 255;     // 0..255
    int t   = threadIdx.x;

    const float* xb = x + (size_t)b * CIN * PLANE + row * HW + t;

    float acc[COUT];
#pragma unroll
    for (int o = 0; o < COUT; ++o) acc[o] = bias[o];

#pragma unroll
    for (int ig = 0; ig < 4; ++ig) {            // i-chunks of 8: bounded MLP, low VGPR
        float xv[8];
#pragma unroll
        for (int j = 0; j < 8; ++j) xv[j] = xb[(size_t)(ig * 8 + j) * PLANE];
#pragma unroll
        for (int o = 0; o < COUT; ++o) {
#pragma unroll
            for (int j = 0; j < 8; ++j)
                acc[o] += Wm[o * CIN + ig * 8 + j] * xv[j];   // uniform -> s_load
        }
    }

    float* fb = feat + (size_t)b * COUT * PLANE + row * HW + t;
#pragma unroll
    for (int o = 0; o < COUT; ++o) fb[(size_t)o * PLANE] = acc[o];

    // ---- pool reduce: row's contribution to filt ----
    __shared__ float lds[COUT * HW];
#pragma unroll
    for (int o = 0; o < COUT; ++o) lds[o * HW + t] = acc[o];
    __syncthreads();

    if (t < COUT * KF) {                   // 160 jobs: (o, xbin l)
        int o  = t / KF;
        int l  = t - o * KF;
        int sl = (l * HW) / KF;
        float s = 0.f;
        for (int w = 0; w < BIN; ++w) s += lds[o * HW + sl + w];
        float* dst = filt_raw + (size_t)(b * COUT + o) * 25 + l;
#pragma unroll
        for (int k = 0; k < KF; ++k) {     // row belongs to 1 or 2 y-bins
            int sk = (k * HW) / KF;
            if (row >= sk && row < sk + BIN) atomicAdd(dst + k * KF, s);
        }
    }
}

// ---------------- K3: depthwise 5x5. 16-row strips; thread = 2 cols x 8 rows ----------
// LDS row: [0..3 pad][cols 0..255 at idx 4..259][260..263 pad]; b64 window reads.
#define LROW 264
#define STRIP 16
__global__ __launch_bounds__(256) void dwconv_kernel(const float* __restrict__ feat,
                                                     const float* __restrict__ filt_raw,
                                                     float* __restrict__ out) {
    int bo    = blockIdx.y;            // 0..255
    int strip = blockIdx.x;            // 0..15
    int gy0   = strip * STRIP;
    int t     = threadIdx.x;

    __shared__ __align__(16) float s[(STRIP + 4) * LROW];   // 21120 B -> 7 blocks/CU
    __shared__ float sfilt[25];
    if (t < 25) sfilt[t] = filt_raw[bo * 25 + t] * (1.0f / (52.0f * 52.0f));
    if (t < 160) {                     // zero pads: 20 rows x 8 cols
        int lr = t >> 3, e = t & 7;
        int ci = (e < 4) ? e : (256 + e);
        s[lr * LROW + ci] = 0.f;
    }

    const float* fb = feat + (size_t)bo * PLANE;
#pragma unroll
    for (int j = 0; j < 5; ++j) {      // 20 rows x 64 float4 = 1280 / 256 threads
        int idx = t + 256 * j;
        int lr  = idx >> 6;
        int cx  = (idx & 63) * 4;
        int gy  = gy0 - 2 + lr;
        float4 v = {0.f, 0.f, 0.f, 0.f};
        if ((unsigned)gy < (unsigned)HW) v = *(const float4*)(fb + gy * HW + cx);
        *(float4*)(&s[lr * LROW + 4 + cx]) = v;
    }
    __syncthreads();

    float fw[25];
#pragma unroll
    for (int j = 0; j < 25; ++j) fw[j] = sfilt[j];   // LDS broadcast once

    int cg  = t & 127;                 // column pair: out cols 2cg, 2cg+1
    int rq  = t >> 7;                  // 0..1 -> out rows 8rq..8rq+7 (local)
    int lr0 = rq * 8;
    int ci0 = 2 * cg + 2;              // window idx base (cols 2cg-2..2cg+3 -> idx ci0..ci0+5)

    float w[5][6];
#pragma unroll
    for (int r = 0; r < 4; ++r) {      // preload 4 rows of the 5-row window
        const float* rp = &s[(lr0 + r) * LROW + ci0];
        float2 a = *(const float2*)(rp);
        float2 c = *(const float2*)(rp + 2);
        float2 e = *(const float2*)(rp + 4);
        w[r][0] = a.x; w[r][1] = a.y; w[r][2] = c.x;
        w[r][3] = c.y; w[r][4] = e.x; w[r][5] = e.y;
    }

    float* ob = out + (size_t)bo * PLANE + (size_t)(gy0 + 8 * rq) * HW + 2 * cg;
#pragma unroll
    for (int r = 0; r < 8; ++r) {
        const float* rp = &s[(lr0 + r + 4) * LROW + ci0];
        float2 a = *(const float2*)(rp);
        float2 c = *(const float2*)(rp + 2);
        float2 e = *(const float2*)(rp + 4);
        w[4][0] = a.x; w[4][1] = a.y; w[4][2] = c.x;
        w[4][3] = c.y; w[4][4] = e.x; w[4][5] = e.y;

        float a0 = 0.f, a1 = 0.f;
#pragma unroll
        for (int kh = 0; kh < 5; ++kh) {
#pragma unroll
            for (int j = 0; j < 5; ++j) {
                float wv = fw[kh * 5 + j];
                a0 += wv * w[kh][j];
                a1 += wv * w[kh][j + 1];
            }
        }
        *(float2*)(ob + r * HW) = make_float2(a0, a1);

#pragma unroll
        for (int kh = 0; kh < 4; ++kh)     // renamed away under full unroll
#pragma unroll
            for (int j = 0; j < 6; ++j) w[kh][j] = w[kh + 1][j];
    }
}

extern "C" void kernel_launch(void* const* d_in, const int* in_sizes, int n_in,
                              void* d_out, int out_size, void* d_ws, size_t ws_size,
                              hipStream_t stream) {
    const float* x      = (const float*)d_in[0];
    const float* conv_w = (const float*)d_in[1];
    const float* conv_b = (const float*)d_in[2];
    float* out = (float*)d_out;

    float* feat = (float*)d_ws;                           // 64 MiB
    float* filt = feat + (size_t)BATCH * COUT * PLANE;    // 6400 floats (raw sums)

    hipMemsetAsync(filt, 0, BATCH * COUT * 25 * sizeof(float), stream);
    conv1x1_pool_kernel<<<dim3(BATCH * 256), dim3(256), 0, stream>>>(x, conv_w, conv_b, feat, filt);
    dwconv_kernel<<<dim3(STRIP, BATCH * COUT), dim3(256), 0, stream>>>(feat, filt, out);
}